// Round 19
// baseline (116.421 us; speedup 1.0000x reference)
//
#include <hip/hip_runtime.h>
#include <math.h>

// force = MLP(|dr|) is piecewise-linear in the scalar edge length -> dense
// fp32 table of force(d) parameterized by u = d/(1+d) (data-independent).
//
// Round-19 = round-18 (38.6us) minus one dispatch:
//  - k4 folded into kcons via last-block-per-range reduction (done[r]
//    counters zeroed by kbin; __threadfence + atomicAdd ordering; the 8th
//    slice-block of each range sums the 8 partials and writes out-gamma*v).
//  - TPTS 4->2 (1024 concurrent table blocks, half per-block chain).
//  kbin (1024 table blocks + 391 bin blocks x 256t): streaming counting-
//      sort of packed uint32 {dloc:11|src:17} into the block's OWN region.
//  kcons (49 ranges x 8 slices = 392 blocks x 512t): LDS x-tile + run
//      prefix + binary search; table lerp; 16 KB LDS acc; partial store;
//      last block per range reduces partials -> out.

#define M_TAB 2048
#define INV_MTAB (1.0f / 2048.0f)
#define EPSF 1e-12f
#define RANGE_N 2048
#define RSHIFT 11
#define NBUCK 64
#define P_SL 8
#define BCHUNK 2048
#define TPTS 2
#define NTABB (M_TAB / TPTS)  // 1024 table blocks
#define MAXRUN 64
#define SRC_BITS 17
#define SRC_MASK 0x1FFFFu

// Table builder: thread j(<128) = neuron j, 2 grid points per task.
__device__ __forceinline__ void build_table2(
    int base, int tid, const float* __restrict__ W0,
    const float* __restrict__ b0, const float* __restrict__ W1,
    const float* __restrict__ b1, const float* __restrict__ W2,
    const float* __restrict__ b2, const float* __restrict__ W3,
    const float* __restrict__ b3, float* __restrict__ table,
    float* bufA, float* bufB) {
  const int j = tid;
  if (j < 128) {
    float w = W0[j], b = b0[j];
#pragma unroll
    for (int p = 0; p < TPTS; ++p) {
      float u = (float)(base + p) * INV_MTAB;
      float dd = u / (1.f - u);
      bufA[j * TPTS + p] = fmaxf(fmaf(dd, w, b), 0.f);
    }
  }
  __syncthreads();
  float acc[TPTS];
  if (j < 128) {
    float b = b1[j];
#pragma unroll
    for (int p = 0; p < TPTS; ++p) acc[p] = b;
#pragma unroll 8
    for (int k = 0; k < 128; ++k) {
      float w = W1[k * 128 + j];
      float2 h = *(const float2*)&bufA[k * TPTS];
      acc[0] = fmaf(h.x, w, acc[0]);
      acc[1] = fmaf(h.y, w, acc[1]);
    }
  }
  __syncthreads();
  if (j < 128) {
#pragma unroll
    for (int p = 0; p < TPTS; ++p) bufB[j * TPTS + p] = fmaxf(acc[p], 0.f);
  }
  __syncthreads();
  if (j < 128) {
    float b = b2[j];
#pragma unroll
    for (int p = 0; p < TPTS; ++p) acc[p] = b;
#pragma unroll 8
    for (int k = 0; k < 128; ++k) {
      float w = W2[k * 128 + j];
      float2 h = *(const float2*)&bufB[k * TPTS];
      acc[0] = fmaf(h.x, w, acc[0]);
      acc[1] = fmaf(h.y, w, acc[1]);
    }
    float w3 = W3[j];
#pragma unroll
    for (int p = 0; p < TPTS; ++p) bufA[j * TPTS + p] = fmaxf(acc[p], 0.f) * w3;
  }
  __syncthreads();
  for (int s = 64; s > 0; s >>= 1) {
    if (j < s) {
#pragma unroll
      for (int p = 0; p < TPTS; ++p)
        bufA[j * TPTS + p] += bufA[(j + s) * TPTS + p];
    }
    __syncthreads();
  }
  if (j < TPTS) table[base + j] = bufA[j] + b3[0];
}

// kbin: blocks < NTABB build table chunk; blocks >= NTABB counting-sort
// their 2048-edge chunk (8/thread) into their OWN region, 4-B entries.
// First bin block also zeroes the done[] counters for kcons.
__global__ __launch_bounds__(256) void kbin(
    const int* __restrict__ src, const int* __restrict__ dst,
    const float* __restrict__ W0, const float* __restrict__ b0,
    const float* __restrict__ W1, const float* __restrict__ b1,
    const float* __restrict__ W2, const float* __restrict__ b2,
    const float* __restrict__ W3, const float* __restrict__ b3,
    unsigned* __restrict__ binData, int* __restrict__ cntTab,
    int* __restrict__ offTab, float* __restrict__ table,
    int* __restrict__ done, int E, int NB) {
  __shared__ float smem[512];  // table bufA/bufB (2 KB)
  __shared__ int cntL[NBUCK];
  __shared__ int offL[NBUCK];
  const int tid = threadIdx.x;
  const int bid = blockIdx.x;

  if (bid < NTABB) {
    build_table2(bid * TPTS, tid, W0, b0, W1, b1, W2, b2, W3, b3, table,
                 smem, smem + 256);
    return;
  }
  const int b = bid - NTABB;
  if (b == 0 && tid < NBUCK) done[tid] = 0;
  if (tid < NBUCK) cntL[tid] = 0;
  __syncthreads();
  const int e0 = b * BCHUNK + tid * 8;
  int mdst[8], msrc[8], mrank[8];
  if (e0 + 7 < E) {
    int4 c0 = *(const int4*)(dst + e0);
    int4 c1 = *(const int4*)(dst + e0 + 4);
    int4 a0 = *(const int4*)(src + e0);
    int4 a1 = *(const int4*)(src + e0 + 4);
    mdst[0] = c0.x; mdst[1] = c0.y; mdst[2] = c0.z; mdst[3] = c0.w;
    mdst[4] = c1.x; mdst[5] = c1.y; mdst[6] = c1.z; mdst[7] = c1.w;
    msrc[0] = a0.x; msrc[1] = a0.y; msrc[2] = a0.z; msrc[3] = a0.w;
    msrc[4] = a1.x; msrc[5] = a1.y; msrc[6] = a1.z; msrc[7] = a1.w;
  } else {
#pragma unroll
    for (int i = 0; i < 8; ++i) {
      bool vv = (e0 + i < E);
      msrc[i] = vv ? src[e0 + i] : 0;
      mdst[i] = vv ? dst[e0 + i] : -1;
    }
  }
#pragma unroll
  for (int i = 0; i < 8; ++i)
    if (mdst[i] >= 0) mrank[i] = atomicAdd(&cntL[mdst[i] >> RSHIFT], 1);
  __syncthreads();
  if (tid == 0) {
    int s = 0;
#pragma unroll
    for (int k = 0; k < NBUCK; ++k) {
      offL[k] = s;
      s += cntL[k];
    }
  }
  __syncthreads();
  if (tid < NBUCK) {
    cntTab[b * NBUCK + tid] = cntL[tid];
    offTab[b * NBUCK + tid] = offL[tid];
  }
  unsigned* gout = binData + (size_t)b * BCHUNK;
#pragma unroll
  for (int i = 0; i < 8; ++i) {
    if (mdst[i] >= 0) {
      int pos = offL[mdst[i] >> RSHIFT] + mrank[i];
      gout[pos] = ((unsigned)(mdst[i] & (RANGE_N - 1)) << SRC_BITS) |
                  (unsigned)msrc[i];
    }
  }
}

// kcons: block (r = bid>>3, p = bid&7): stage x[range r] in LDS, consume
// runs of bin-blocks b%8==p via run-prefix + binary search, accumulate in
// LDS, store partial copy p. Last block per range reduces all P_SL
// partials and writes out = sum - gamma*v.
__global__ __launch_bounds__(512) void kcons(
    const unsigned* __restrict__ binData, const int* __restrict__ cntTab,
    const int* __restrict__ offTab, const float* __restrict__ table,
    const float* __restrict__ x, const float* __restrict__ v,
    const float* __restrict__ gamma, float* __restrict__ partial,
    int* __restrict__ done, float* __restrict__ out, int NB, int n_nodes,
    int n_out) {
  __shared__ float acc[RANGE_N * 2];  // 16 KB
  __shared__ float2 xl[RANGE_N];      // 16 KB
  __shared__ int runStart[MAXRUN];
  __shared__ int pref[MAXRUN + 1];
  __shared__ int isLast;
  const int tid = threadIdx.x;
  const int p = blockIdx.x & (P_SL - 1);
  const int r = blockIdx.x >> 3;
  const int node0 = r * RANGE_N;

  for (int i = tid; i < RANGE_N * 2; i += 512) acc[i] = 0.f;
  for (int i = tid; i < RANGE_N; i += 512)
    xl[i] = (node0 + i < n_nodes) ? ((const float2*)x)[node0 + i]
                                  : make_float2(0.f, 0.f);
  const int nrun = (NB - p + P_SL - 1) / P_SL;
  for (int j = tid; j < nrun; j += 512) {
    int b = p + j * P_SL;
    runStart[j] = b * BCHUNK + offTab[b * NBUCK + r];
    pref[j + 1] = cntTab[b * NBUCK + r];
  }
  __syncthreads();
  if (tid == 0) {
    pref[0] = 0;
    for (int j = 0; j < nrun; ++j) pref[j + 1] += pref[j];
  }
  __syncthreads();

  const int T = pref[nrun];
  for (int g = tid; g < T; g += 512) {
    int lo = 0, hi = nrun;
    while (hi - lo > 1) {
      int mid = (lo + hi) >> 1;
      if (pref[mid] <= g) lo = mid; else hi = mid;
    }
    unsigned ent = binData[(size_t)runStart[lo] + (g - pref[lo])];
    int dloc = (int)(ent >> SRC_BITS);
    int s = (int)(ent & SRC_MASK);
    float2 xs = ((const float2*)x)[s];
    float2 xt = xl[dloc];
    float dx = xt.x - xs.x, dy = xt.y - xs.y;
    float d = sqrtf(fmaf(dx, dx, dy * dy));
    float u = d / (1.f + d);
    float idxf = u * (float)M_TAB;
    int i0 = (int)idxf;
    if (i0 > M_TAB - 2) i0 = M_TAB - 2;
    float frac = idxf - (float)i0;
    float f0 = table[i0], f1 = table[i0 + 1];
    float f = fmaf(frac, f1 - f0, f0);
    float sc = f / fmaxf(d, EPSF);
    atomicAdd(&acc[dloc * 2], sc * dx);
    atomicAdd(&acc[dloc * 2 + 1], sc * dy);
  }
  __syncthreads();

  const int cnt2 = min(RANGE_N, n_nodes - node0);
  float2* po = (float2*)(partial + (size_t)p * n_out) + node0;
  const float2* a2 = (const float2*)acc;
  for (int i = tid; i < cnt2; i += 512) po[i] = a2[i];

  // Last block per range sums the P_SL partials -> out.
  __syncthreads();
  if (tid == 0) {
    __threadfence();
    int t = atomicAdd(&done[r], 1);
    isLast = (t == P_SL - 1);
  }
  __syncthreads();
  if (isLast) {
    __threadfence();
    const float gm = -gamma[0];
    const float2* pv = (const float2*)v + node0;
    float2* po2 = (float2*)out + node0;
    for (int i = tid; i < cnt2; i += 512) {
      float2 s = make_float2(0.f, 0.f);
#pragma unroll
      for (int c = 0; c < P_SL; ++c) {
        float2 pp = ((const float2*)(partial + (size_t)c * n_out))[node0 + i];
        s.x += pp.x;
        s.y += pp.y;
      }
      float2 vv = pv[i];
      po2[i] = make_float2(fmaf(gm, vv.x, s.x), fmaf(gm, vv.y, s.y));
    }
  }
}

// ---- Fallback path (tiny d_ws only) ----
__global__ __launch_bounds__(128) void k2_table(
    const float* __restrict__ W0, const float* __restrict__ b0,
    const float* __restrict__ W1, const float* __restrict__ b1,
    const float* __restrict__ W2, const float* __restrict__ b2,
    const float* __restrict__ W3, const float* __restrict__ b3,
    float* __restrict__ table) {
  __shared__ float bufA[256];
  __shared__ float bufB[256];
  build_table2(blockIdx.x * TPTS, threadIdx.x, W0, b0, W1, b1, W2, b2, W3,
               b3, table, bufA, bufB);
}

__global__ __launch_bounds__(256) void k0_init(const float* __restrict__ v,
                                               const float* __restrict__ gamma,
                                               float* __restrict__ out,
                                               int n) {
  int i = blockIdx.x * blockDim.x + threadIdx.x;
  if (i < n) out[i] = -gamma[0] * v[i];
}

__global__ __launch_bounds__(256) void k3_direct(
    const float* __restrict__ x, const int* __restrict__ src,
    const int* __restrict__ dst, const float* __restrict__ table,
    float* __restrict__ out, int E) {
  int e = blockIdx.x * blockDim.x + threadIdx.x;
  if (e >= E) return;
  int s = src[e], t = dst[e];
  float2 xs = ((const float2*)x)[s];
  float2 xt = ((const float2*)x)[t];
  float dx = xt.x - xs.x, dy = xt.y - xs.y;
  float d = sqrtf(fmaf(dx, dx, dy * dy));
  float u = d / (1.f + d);
  float idxf = u * (float)M_TAB;
  int i0 = (int)idxf;
  if (i0 > M_TAB - 2) i0 = M_TAB - 2;
  float frac = idxf - (float)i0;
  float f = fmaf(frac, table[i0 + 1] - table[i0], table[i0]);
  float sc = f / fmaxf(d, EPSF);
  atomicAdd(&out[2 * t + 0], sc * dx);
  atomicAdd(&out[2 * t + 1], sc * dy);
}

extern "C" void kernel_launch(void* const* d_in, const int* in_sizes, int n_in,
                              void* d_out, int out_size, void* d_ws,
                              size_t ws_size, hipStream_t stream) {
  const float* x = (const float*)d_in[0];
  const float* v = (const float*)d_in[1];
  const int* src = (const int*)d_in[2];
  const int* dst = (const int*)d_in[3];
  const float* gamma = (const float*)d_in[4];
  const float* W0 = (const float*)d_in[5];
  const float* b0 = (const float*)d_in[6];
  const float* W1 = (const float*)d_in[7];
  const float* b1 = (const float*)d_in[8];
  const float* W2 = (const float*)d_in[9];
  const float* b2 = (const float*)d_in[10];
  const float* W3 = (const float*)d_in[11];
  const float* b3 = (const float*)d_in[12];
  float* out = (float*)d_out;
  float* table = (float*)d_ws;

  int n_out = out_size;           // 200000
  int n_nodes = in_sizes[0] / 2;  // 100000
  int E = in_sizes[2];            // 800000

  const int NB = (E + BCHUNK - 1) / BCHUNK;          // 391
  const int NR = (n_nodes + RANGE_N - 1) / RANGE_N;  // 49
  size_t sz_tab = ((size_t)NB * NBUCK * 4 + 255) & ~(size_t)255;
  size_t off_cnt = 65536;
  size_t off_off = off_cnt + sz_tab;
  size_t off_done = off_off + sz_tab;
  size_t off_part = off_done + 1024;
  size_t off_bin = off_part + (size_t)P_SL * n_out * 4;
  size_t need = off_bin + (size_t)NB * BCHUNK * 4;

  bool fast = (ws_size >= need) && (n_out == 2 * n_nodes) &&
              (n_nodes <= (1 << SRC_BITS)) && (NR <= NBUCK) &&
              (NB <= P_SL * MAXRUN) && ((n_out & 3) == 0);

  if (fast) {
    int* cntTab = (int*)((char*)d_ws + off_cnt);
    int* offTab = (int*)((char*)d_ws + off_off);
    int* done = (int*)((char*)d_ws + off_done);
    float* partial = (float*)((char*)d_ws + off_part);
    unsigned* binData = (unsigned*)((char*)d_ws + off_bin);
    hipLaunchKernelGGL(kbin, dim3(NTABB + NB), dim3(256), 0, stream, src, dst,
                       W0, b0, W1, b1, W2, b2, W3, b3, binData, cntTab,
                       offTab, table, done, E, NB);
    hipLaunchKernelGGL(kcons, dim3(NR * P_SL), dim3(512), 0, stream, binData,
                       cntTab, offTab, table, x, v, gamma, partial, done, out,
                       NB, n_nodes, n_out);
  } else {
    hipLaunchKernelGGL(k2_table, dim3(NTABB), dim3(128), 0, stream, W0, b0,
                       W1, b1, W2, b2, W3, b3, table);
    hipLaunchKernelGGL(k0_init, dim3((n_out + 255) / 256), dim3(256), 0,
                       stream, v, gamma, out, n_out);
    hipLaunchKernelGGL(k3_direct, dim3((E + 255) / 256), dim3(256), 0, stream,
                       x, src, dst, table, out, E);
  }
}

// Round 20
// 38.548 us; speedup vs baseline: 3.0202x; 3.0202x over previous
//
#include <hip/hip_runtime.h>
#include <math.h>

// force = MLP(|dr|) is piecewise-linear in the scalar edge length -> dense
// fp32 table of force(d) parameterized by u = d/(1+d) (data-independent).
//
// Round-20 = round-18 (best, 38.6us) exactly, with TPTS 4->2 (1024
// concurrent table blocks, half per-block serial chain). Round-19 lesson:
// in-kernel __threadfence (device scope) costs a cross-XCD L2 writeback
// per call on gfx950 (~100us aggregate) -- the k4 dispatch boundary is the
// CHEAP way to get producer-consumer visibility. 3 dispatches:
//  kbin (1024 table blocks + 391 bin blocks x 256t): streaming counting-
//      sort of packed uint32 {dloc:11|src:17} into the block's OWN region.
//  kcons (49 ranges x 8 slices = 392 blocks x 512t): LDS x-tile + run
//      prefix + binary search; table lerp; 16 KB LDS acc; store partial p.
//  k4: out = -gamma*v + sum of 8 partials.

#define M_TAB 2048
#define INV_MTAB (1.0f / 2048.0f)
#define EPSF 1e-12f
#define RANGE_N 2048
#define RSHIFT 11
#define NBUCK 64
#define P_SL 8
#define BCHUNK 2048
#define TPTS 2
#define NTABB (M_TAB / TPTS)  // 1024 table blocks
#define MAXRUN 64
#define SRC_BITS 17
#define SRC_MASK 0x1FFFFu

// Table builder: thread j(<128) = neuron j, 2 grid points per task.
__device__ __forceinline__ void build_table2(
    int base, int tid, const float* __restrict__ W0,
    const float* __restrict__ b0, const float* __restrict__ W1,
    const float* __restrict__ b1, const float* __restrict__ W2,
    const float* __restrict__ b2, const float* __restrict__ W3,
    const float* __restrict__ b3, float* __restrict__ table,
    float* bufA, float* bufB) {
  const int j = tid;
  if (j < 128) {
    float w = W0[j], b = b0[j];
#pragma unroll
    for (int p = 0; p < TPTS; ++p) {
      float u = (float)(base + p) * INV_MTAB;
      float dd = u / (1.f - u);
      bufA[j * TPTS + p] = fmaxf(fmaf(dd, w, b), 0.f);
    }
  }
  __syncthreads();
  float acc[TPTS];
  if (j < 128) {
    float b = b1[j];
#pragma unroll
    for (int p = 0; p < TPTS; ++p) acc[p] = b;
#pragma unroll 8
    for (int k = 0; k < 128; ++k) {
      float w = W1[k * 128 + j];
      float2 h = *(const float2*)&bufA[k * TPTS];
      acc[0] = fmaf(h.x, w, acc[0]);
      acc[1] = fmaf(h.y, w, acc[1]);
    }
  }
  __syncthreads();
  if (j < 128) {
#pragma unroll
    for (int p = 0; p < TPTS; ++p) bufB[j * TPTS + p] = fmaxf(acc[p], 0.f);
  }
  __syncthreads();
  if (j < 128) {
    float b = b2[j];
#pragma unroll
    for (int p = 0; p < TPTS; ++p) acc[p] = b;
#pragma unroll 8
    for (int k = 0; k < 128; ++k) {
      float w = W2[k * 128 + j];
      float2 h = *(const float2*)&bufB[k * TPTS];
      acc[0] = fmaf(h.x, w, acc[0]);
      acc[1] = fmaf(h.y, w, acc[1]);
    }
    float w3 = W3[j];
#pragma unroll
    for (int p = 0; p < TPTS; ++p) bufA[j * TPTS + p] = fmaxf(acc[p], 0.f) * w3;
  }
  __syncthreads();
  for (int s = 64; s > 0; s >>= 1) {
    if (j < s) {
#pragma unroll
      for (int p = 0; p < TPTS; ++p)
        bufA[j * TPTS + p] += bufA[(j + s) * TPTS + p];
    }
    __syncthreads();
  }
  if (j < TPTS) table[base + j] = bufA[j] + b3[0];
}

// kbin: blocks < NTABB build table chunk; blocks >= NTABB counting-sort
// their 2048-edge chunk (8/thread) into their OWN region, 4-B entries.
__global__ __launch_bounds__(256) void kbin(
    const int* __restrict__ src, const int* __restrict__ dst,
    const float* __restrict__ W0, const float* __restrict__ b0,
    const float* __restrict__ W1, const float* __restrict__ b1,
    const float* __restrict__ W2, const float* __restrict__ b2,
    const float* __restrict__ W3, const float* __restrict__ b3,
    unsigned* __restrict__ binData, int* __restrict__ cntTab,
    int* __restrict__ offTab, float* __restrict__ table, int E, int NB) {
  __shared__ float smem[512];  // table bufA/bufB (2 KB)
  __shared__ int cntL[NBUCK];
  __shared__ int offL[NBUCK];
  const int tid = threadIdx.x;
  const int bid = blockIdx.x;

  if (bid < NTABB) {
    build_table2(bid * TPTS, tid, W0, b0, W1, b1, W2, b2, W3, b3, table,
                 smem, smem + 256);
    return;
  }
  const int b = bid - NTABB;
  if (tid < NBUCK) cntL[tid] = 0;
  __syncthreads();
  const int e0 = b * BCHUNK + tid * 8;
  int mdst[8], msrc[8], mrank[8];
  if (e0 + 7 < E) {
    int4 c0 = *(const int4*)(dst + e0);
    int4 c1 = *(const int4*)(dst + e0 + 4);
    int4 a0 = *(const int4*)(src + e0);
    int4 a1 = *(const int4*)(src + e0 + 4);
    mdst[0] = c0.x; mdst[1] = c0.y; mdst[2] = c0.z; mdst[3] = c0.w;
    mdst[4] = c1.x; mdst[5] = c1.y; mdst[6] = c1.z; mdst[7] = c1.w;
    msrc[0] = a0.x; msrc[1] = a0.y; msrc[2] = a0.z; msrc[3] = a0.w;
    msrc[4] = a1.x; msrc[5] = a1.y; msrc[6] = a1.z; msrc[7] = a1.w;
  } else {
#pragma unroll
    for (int i = 0; i < 8; ++i) {
      bool vv = (e0 + i < E);
      msrc[i] = vv ? src[e0 + i] : 0;
      mdst[i] = vv ? dst[e0 + i] : -1;
    }
  }
#pragma unroll
  for (int i = 0; i < 8; ++i)
    if (mdst[i] >= 0) mrank[i] = atomicAdd(&cntL[mdst[i] >> RSHIFT], 1);
  __syncthreads();
  if (tid == 0) {
    int s = 0;
#pragma unroll
    for (int k = 0; k < NBUCK; ++k) {
      offL[k] = s;
      s += cntL[k];
    }
  }
  __syncthreads();
  if (tid < NBUCK) {
    cntTab[b * NBUCK + tid] = cntL[tid];
    offTab[b * NBUCK + tid] = offL[tid];
  }
  unsigned* gout = binData + (size_t)b * BCHUNK;
#pragma unroll
  for (int i = 0; i < 8; ++i) {
    if (mdst[i] >= 0) {
      int pos = offL[mdst[i] >> RSHIFT] + mrank[i];
      gout[pos] = ((unsigned)(mdst[i] & (RANGE_N - 1)) << SRC_BITS) |
                  (unsigned)msrc[i];
    }
  }
}

// kcons: block (r = bid>>3, p = bid&7): stage x[range r] in LDS, consume
// runs of bin-blocks b%8==p via run-prefix + binary search, full edge math
// in fp32 (one x[src] gather/edge), accumulate, store partial copy p.
__global__ __launch_bounds__(512) void kcons(
    const unsigned* __restrict__ binData, const int* __restrict__ cntTab,
    const int* __restrict__ offTab, const float* __restrict__ table,
    const float* __restrict__ x, float* __restrict__ partial, int NB,
    int n_nodes, int n_out) {
  __shared__ float acc[RANGE_N * 2];  // 16 KB
  __shared__ float2 xl[RANGE_N];      // 16 KB
  __shared__ int runStart[MAXRUN];
  __shared__ int pref[MAXRUN + 1];
  const int tid = threadIdx.x;
  const int p = blockIdx.x & (P_SL - 1);
  const int r = blockIdx.x >> 3;
  const int node0 = r * RANGE_N;

  for (int i = tid; i < RANGE_N * 2; i += 512) acc[i] = 0.f;
  for (int i = tid; i < RANGE_N; i += 512)
    xl[i] = (node0 + i < n_nodes) ? ((const float2*)x)[node0 + i]
                                  : make_float2(0.f, 0.f);
  const int nrun = (NB - p + P_SL - 1) / P_SL;
  for (int j = tid; j < nrun; j += 512) {
    int b = p + j * P_SL;
    runStart[j] = b * BCHUNK + offTab[b * NBUCK + r];
    pref[j + 1] = cntTab[b * NBUCK + r];
  }
  __syncthreads();
  if (tid == 0) {
    pref[0] = 0;
    for (int j = 0; j < nrun; ++j) pref[j + 1] += pref[j];
  }
  __syncthreads();

  const int T = pref[nrun];
  for (int g = tid; g < T; g += 512) {
    int lo = 0, hi = nrun;
    while (hi - lo > 1) {
      int mid = (lo + hi) >> 1;
      if (pref[mid] <= g) lo = mid; else hi = mid;
    }
    unsigned ent = binData[(size_t)runStart[lo] + (g - pref[lo])];
    int dloc = (int)(ent >> SRC_BITS);
    int s = (int)(ent & SRC_MASK);
    float2 xs = ((const float2*)x)[s];
    float2 xt = xl[dloc];
    float dx = xt.x - xs.x, dy = xt.y - xs.y;
    float d = sqrtf(fmaf(dx, dx, dy * dy));
    float u = d / (1.f + d);
    float idxf = u * (float)M_TAB;
    int i0 = (int)idxf;
    if (i0 > M_TAB - 2) i0 = M_TAB - 2;
    float frac = idxf - (float)i0;
    float f0 = table[i0], f1 = table[i0 + 1];
    float f = fmaf(frac, f1 - f0, f0);
    float sc = f / fmaxf(d, EPSF);
    atomicAdd(&acc[dloc * 2], sc * dx);
    atomicAdd(&acc[dloc * 2 + 1], sc * dy);
  }
  __syncthreads();

  const int cnt2 = min(RANGE_N, n_nodes - node0);
  float2* po = (float2*)(partial + (size_t)p * n_out) + node0;
  const float2* a2 = (const float2*)acc;
  for (int i = tid; i < cnt2; i += 512) po[i] = a2[i];
}

// k4: out = -gamma*v + sum_{p<8} partial[p].
__global__ __launch_bounds__(256) void k4_finish(
    const float4* __restrict__ v4, const float* __restrict__ gamma,
    const float4* __restrict__ part4, float4* __restrict__ out4, int n4) {
  int i = blockIdx.x * blockDim.x + threadIdx.x;
  if (i >= n4) return;
  float g = -gamma[0];
  float4 a = v4[i];
  float4 acc = make_float4(g * a.x, g * a.y, g * a.z, g * a.w);
#pragma unroll
  for (int c = 0; c < P_SL; ++c) {
    float4 p = part4[(size_t)c * n4 + i];
    acc.x += p.x;
    acc.y += p.y;
    acc.z += p.z;
    acc.w += p.w;
  }
  out4[i] = acc;
}

// ---- Fallback path (tiny d_ws only) ----
__global__ __launch_bounds__(128) void k2_table(
    const float* __restrict__ W0, const float* __restrict__ b0,
    const float* __restrict__ W1, const float* __restrict__ b1,
    const float* __restrict__ W2, const float* __restrict__ b2,
    const float* __restrict__ W3, const float* __restrict__ b3,
    float* __restrict__ table) {
  __shared__ float bufA[256];
  __shared__ float bufB[256];
  build_table2(blockIdx.x * TPTS, threadIdx.x, W0, b0, W1, b1, W2, b2, W3,
               b3, table, bufA, bufB);
}

__global__ __launch_bounds__(256) void k0_init(const float* __restrict__ v,
                                               const float* __restrict__ gamma,
                                               float* __restrict__ out,
                                               int n) {
  int i = blockIdx.x * blockDim.x + threadIdx.x;
  if (i < n) out[i] = -gamma[0] * v[i];
}

__global__ __launch_bounds__(256) void k3_direct(
    const float* __restrict__ x, const int* __restrict__ src,
    const int* __restrict__ dst, const float* __restrict__ table,
    float* __restrict__ out, int E) {
  int e = blockIdx.x * blockDim.x + threadIdx.x;
  if (e >= E) return;
  int s = src[e], t = dst[e];
  float2 xs = ((const float2*)x)[s];
  float2 xt = ((const float2*)x)[t];
  float dx = xt.x - xs.x, dy = xt.y - xs.y;
  float d = sqrtf(fmaf(dx, dx, dy * dy));
  float u = d / (1.f + d);
  float idxf = u * (float)M_TAB;
  int i0 = (int)idxf;
  if (i0 > M_TAB - 2) i0 = M_TAB - 2;
  float frac = idxf - (float)i0;
  float f = fmaf(frac, table[i0 + 1] - table[i0], table[i0]);
  float sc = f / fmaxf(d, EPSF);
  atomicAdd(&out[2 * t + 0], sc * dx);
  atomicAdd(&out[2 * t + 1], sc * dy);
}

extern "C" void kernel_launch(void* const* d_in, const int* in_sizes, int n_in,
                              void* d_out, int out_size, void* d_ws,
                              size_t ws_size, hipStream_t stream) {
  const float* x = (const float*)d_in[0];
  const float* v = (const float*)d_in[1];
  const int* src = (const int*)d_in[2];
  const int* dst = (const int*)d_in[3];
  const float* gamma = (const float*)d_in[4];
  const float* W0 = (const float*)d_in[5];
  const float* b0 = (const float*)d_in[6];
  const float* W1 = (const float*)d_in[7];
  const float* b1 = (const float*)d_in[8];
  const float* W2 = (const float*)d_in[9];
  const float* b2 = (const float*)d_in[10];
  const float* W3 = (const float*)d_in[11];
  const float* b3 = (const float*)d_in[12];
  float* out = (float*)d_out;
  float* table = (float*)d_ws;

  int n_out = out_size;           // 200000
  int n_nodes = in_sizes[0] / 2;  // 100000
  int E = in_sizes[2];            // 800000

  const int NB = (E + BCHUNK - 1) / BCHUNK;          // 391
  const int NR = (n_nodes + RANGE_N - 1) / RANGE_N;  // 49
  size_t sz_tab = ((size_t)NB * NBUCK * 4 + 255) & ~(size_t)255;
  size_t off_cnt = 65536;
  size_t off_off = off_cnt + sz_tab;
  size_t off_part = off_off + sz_tab;
  size_t off_bin = off_part + (size_t)P_SL * n_out * 4;
  size_t need = off_bin + (size_t)NB * BCHUNK * 4;

  bool fast = (ws_size >= need) && (n_out == 2 * n_nodes) &&
              (n_nodes <= (1 << SRC_BITS)) && (NR <= NBUCK) &&
              (NB <= P_SL * MAXRUN) && ((n_out & 3) == 0);

  if (fast) {
    int* cntTab = (int*)((char*)d_ws + off_cnt);
    int* offTab = (int*)((char*)d_ws + off_off);
    float* partial = (float*)((char*)d_ws + off_part);
    unsigned* binData = (unsigned*)((char*)d_ws + off_bin);
    hipLaunchKernelGGL(kbin, dim3(NTABB + NB), dim3(256), 0, stream, src, dst,
                       W0, b0, W1, b1, W2, b2, W3, b3, binData, cntTab,
                       offTab, table, E, NB);
    hipLaunchKernelGGL(kcons, dim3(NR * P_SL), dim3(512), 0, stream, binData,
                       cntTab, offTab, table, x, partial, NB, n_nodes, n_out);
    hipLaunchKernelGGL(k4_finish, dim3((n_out / 4 + 255) / 256), dim3(256), 0,
                       stream, (const float4*)v, gamma, (const float4*)partial,
                       (float4*)out, n_out / 4);
  } else {
    hipLaunchKernelGGL(k2_table, dim3(NTABB), dim3(128), 0, stream, W0, b0,
                       W1, b1, W2, b2, W3, b3, table);
    hipLaunchKernelGGL(k0_init, dim3((n_out + 255) / 256), dim3(256), 0,
                       stream, v, gamma, out, n_out);
    hipLaunchKernelGGL(k3_direct, dim3((E + 255) / 256), dim3(256), 0, stream,
                       x, src, dst, table, out, E);
  }
}